// Round 2
// baseline (472.240 us; speedup 1.0000x reference)
//
#include <hip/hip_runtime.h>

// ---------------- types ----------------
typedef __bf16 bf16;
typedef __bf16 bf16x4 __attribute__((ext_vector_type(4)));
typedef __bf16 bf16x8 __attribute__((ext_vector_type(8)));
typedef float f32x4 __attribute__((ext_vector_type(4)));

#define AS1C(p) ((const __attribute__((address_space(1))) void*)(p))
#define AS3(p)  ((__attribute__((address_space(3))) void*)(p))

__device__ __forceinline__ void gld16(const bf16* gsrc, bf16* ldst) {
  // async global->LDS, 16 bytes/lane; LDS dest must be wave-uniform base (HW adds lane*16)
  __builtin_amdgcn_global_load_lds(AS1C(gsrc), AS3(ldst), 16, 0, 0);
}

// B=2, S=2048, D=1024, H=16, DH=64; M = B*S = 4096

// ---------------- cast x to bf16 ----------------
__global__ void castx_kernel(const float* __restrict__ x, bf16* __restrict__ xb) {
  const int n4 = (4096 * 1024) / 4;
  for (int i = blockIdx.x * blockDim.x + threadIdx.x; i < n4; i += gridDim.x * blockDim.x) {
    float4 v = ((const float4*)x)[i];
    bf16x4 o;
    o[0] = (bf16)v.x; o[1] = (bf16)v.y; o[2] = (bf16)v.z; o[3] = (bf16)v.w;
    ((bf16x4*)xb)[i] = o;
  }
}

// ---------------- prep weights: Wqkv (Q pre-scaled 1/8), Wo2 transpose, scaled biases ----------------
__global__ void prep_kernel(const float* __restrict__ WQ, const float* __restrict__ WK,
                            const float* __restrict__ WV, const float* __restrict__ WO,
                            const float* __restrict__ bQ, const float* __restrict__ bK,
                            const float* __restrict__ bV,
                            bf16* __restrict__ Wqkv, bf16* __restrict__ Wo2,
                            float* __restrict__ biasq) {
  const int WN = 1024 * 1024;
  const int total = 4 * WN + 3072;
  for (int i = blockIdx.x * blockDim.x + threadIdx.x; i < total; i += gridDim.x * blockDim.x) {
    if (i < WN) {
      Wqkv[i] = (bf16)(WQ[i] * 0.125f);          // fold 1/sqrt(DH) into Q
    } else if (i < 2 * WN) {
      Wqkv[i] = (bf16)WK[i - WN];
    } else if (i < 3 * WN) {
      Wqkv[i] = (bf16)WV[i - 2 * WN];
    } else if (i < 4 * WN) {
      int j = i - 3 * WN;                         // W_O flat [H][D][DH]
      int hh = j >> 16, r = j & 65535, d = r >> 6, dh = r & 63;
      Wo2[d * 1024 + hh * 64 + dh] = (bf16)WO[j]; // Wo2[d][h*64+dh]
    } else {
      int n = i - 4 * WN;
      biasq[n] = (n < 1024) ? bQ[n] * 0.125f : (n < 2048) ? bK[n - 1024] : bV[n - 2048];
    }
  }
}

// ---------------- GEMM C[M,N] = A[M,K] * Bw[N,K]^T  (bf16 in, f32 acc) ----------------
// MODE 0: QKV projection -> scatter Q[B,H,S,DH], K[B,H,S,DH], Vt[B,H,DH,S] (bf16, +bias)
// MODE 1: out projection -> Co[M,N] f32 (+bias)
template <int MODE>
__global__ __launch_bounds__(256)
void gemm_bt(const bf16* __restrict__ A, const bf16* __restrict__ Bw,
             const float* __restrict__ bias,
             bf16* __restrict__ Qo, bf16* __restrict__ Ko, bf16* __restrict__ Vt,
             float* __restrict__ Co, int M, int N, int K) {
  __shared__ bf16 As[128 * 64];
  __shared__ bf16 Bs[128 * 64];
  const int tid = threadIdx.x;
  const int lane = tid & 63, w = tid >> 6;
  const int wr = w >> 1, wc = w & 1;
  const int g = lane >> 4, lr = lane & 15;
  const int brow = blockIdx.x * 128, bcol = blockIdx.y * 128;

  f32x4 acc[4][4] = {};

  for (int k0 = 0; k0 < K; k0 += 64) {
#pragma unroll
    for (int it = 0; it < 4; ++it) {
      const int chunk = it * 4 + w;          // wave-uniform
      const int e = chunk * 64 + lane;       // 16B chunk id in tile
      const int row = e >> 3;
      const int c8 = (e & 7) << 3;
      gld16(A + (size_t)(brow + row) * K + k0 + c8, As + chunk * 512);
      gld16(Bw + (size_t)(bcol + row) * K + k0 + c8, Bs + chunk * 512);
    }
    __syncthreads();                          // drains vmcnt: tiles ready
#pragma unroll
    for (int kk = 0; kk < 2; ++kk) {
      bf16x8 af[4], bfm[4];
#pragma unroll
      for (int m = 0; m < 4; ++m)
        af[m] = *(const bf16x8*)(As + (wr * 64 + m * 16 + lr) * 64 + kk * 32 + g * 8);
#pragma unroll
      for (int n = 0; n < 4; ++n)
        bfm[n] = *(const bf16x8*)(Bs + (wc * 64 + n * 16 + lr) * 64 + kk * 32 + g * 8);
#pragma unroll
      for (int m = 0; m < 4; ++m)
#pragma unroll
        for (int n = 0; n < 4; ++n)
          acc[m][n] = __builtin_amdgcn_mfma_f32_16x16x32_bf16(af[m], bfm[n], acc[m][n], 0, 0, 0);
    }
    __syncthreads();                          // protect LDS before next stage
  }

  const int row0 = brow + wr * 64;
  const int col0 = bcol + wc * 64;
#pragma unroll
  for (int m = 0; m < 4; ++m) {
#pragma unroll
    for (int n = 0; n < 4; ++n) {
      const int nidx = col0 + n * 16 + lr;
      f32x4 v = acc[m][n];
      const float bs = bias[nidx];
      if (MODE == 0) {
        const int stream = nidx >> 10;        // 0=Q 1=K 2=V (uniform per 16-lane group)
        const int j = nidx & 1023;
        const int hh = j >> 6, dh = j & 63;
        const int r0 = row0 + m * 16 + g * 4; // token row base; i = 0..3 consecutive
        const int b = r0 >> 11;
        const int p0 = r0 & 2047;
        if (stream == 2) {
          bf16x4 vv;
#pragma unroll
          for (int i = 0; i < 4; ++i) vv[i] = (bf16)(v[i] + bs);
          *(bf16x4*)(Vt + ((size_t)(b * 16 + hh) * 64 + dh) * 2048 + p0) = vv;
        } else {
          bf16* dst = (stream == 0) ? Qo : Ko;
#pragma unroll
          for (int i = 0; i < 4; ++i)
            dst[((size_t)(b * 16 + hh) * 2048 + (p0 + i)) * 64 + dh] = (bf16)(v[i] + bs);
        }
      } else {
#pragma unroll
        for (int i = 0; i < 4; ++i) {
          const int r = row0 + m * 16 + g * 4 + i;
          Co[(size_t)r * 1024 + nidx] = v[i] + bs;
        }
      }
    }
  }
}

// ---------------- causal flash attention ----------------
// grid: (S/64, H, B); block 256 = 4 waves, each wave owns 16 q-rows.
// Q,K: [B,H,S,DH] bf16 (Q pre-scaled); V: [B,H,DH,S] bf16 (transposed). Z out: [B,S,H,DH] bf16.
__global__ __launch_bounds__(256)
void attn_kernel(const bf16* __restrict__ Qm, const bf16* __restrict__ Km,
                 const bf16* __restrict__ Vm, bf16* __restrict__ Z) {
  const int qt = blockIdx.x, hh = blockIdx.y, b = blockIdx.z;
  const int bh = b * 16 + hh;
  const int lane = threadIdx.x & 63, w = threadIdx.x >> 6;
  const int g = lane >> 4, lr = lane & 15;
  __shared__ bf16 Plds[4][16][72];           // wave-private P tile, padded (144B row stride)

  const bf16* Qb = Qm + (size_t)bh * 2048 * 64;
  const bf16* Kb = Km + (size_t)bh * 2048 * 64;
  const bf16* Vb = Vm + (size_t)bh * 64 * 2048;
  const int q0 = qt * 64 + w * 16;

  bf16x8 aq[2];
#pragma unroll
  for (int kk = 0; kk < 2; ++kk)
    aq[kk] = *(const bf16x8*)(Qb + (size_t)(q0 + lr) * 64 + kk * 32 + g * 8);

  float m_i[4], l_i[4];
  f32x4 oacc[4] = {};
#pragma unroll
  for (int i = 0; i < 4; ++i) { m_i[i] = -1e30f; l_i[i] = 0.f; }

  for (int t = 0; t <= qt; ++t) {
    const int kv0 = t * 64;
    f32x4 s[4] = {};
#pragma unroll
    for (int kk = 0; kk < 2; ++kk) {
#pragma unroll
      for (int n = 0; n < 4; ++n) {
        bf16x8 bk = *(const bf16x8*)(Kb + (size_t)(kv0 + n * 16 + lr) * 64 + kk * 32 + g * 8);
        s[n] = __builtin_amdgcn_mfma_f32_16x16x32_bf16(aq[kk], bk, s[n], 0, 0, 0);
      }
    }
    if (t == qt) {                           // diagonal tile: causal mask
#pragma unroll
      for (int n = 0; n < 4; ++n) {
        const int key = n * 16 + lr;
#pragma unroll
        for (int i = 0; i < 4; ++i) {
          const int rr = w * 16 + g * 4 + i;
          if (key > rr) s[n][i] = -1e9f;
        }
      }
    }
    float tm[4], ts[4], al[4];
#pragma unroll
    for (int i = 0; i < 4; ++i)
      tm[i] = fmaxf(fmaxf(s[0][i], s[1][i]), fmaxf(s[2][i], s[3][i]));
#pragma unroll
    for (int d = 1; d < 16; d <<= 1)
#pragma unroll
      for (int i = 0; i < 4; ++i) tm[i] = fmaxf(tm[i], __shfl_xor(tm[i], d));
#pragma unroll
    for (int i = 0; i < 4; ++i) {
      const float mn = fmaxf(m_i[i], tm[i]);
      al[i] = __expf(m_i[i] - mn);
      m_i[i] = mn;
    }
    f32x4 p[4];
#pragma unroll
    for (int n = 0; n < 4; ++n)
#pragma unroll
      for (int i = 0; i < 4; ++i) p[n][i] = __expf(s[n][i] - m_i[i]);
#pragma unroll
    for (int i = 0; i < 4; ++i) ts[i] = p[0][i] + p[1][i] + p[2][i] + p[3][i];
#pragma unroll
    for (int d = 1; d < 16; d <<= 1)
#pragma unroll
      for (int i = 0; i < 4; ++i) ts[i] += __shfl_xor(ts[i], d);
#pragma unroll
    for (int i = 0; i < 4; ++i) l_i[i] = l_i[i] * al[i] + ts[i];
#pragma unroll
    for (int n = 0; n < 4; ++n)
#pragma unroll
      for (int i = 0; i < 4; ++i) oacc[n][i] *= al[i];
    // P -> LDS (C-layout write), read back in A-frag layout
#pragma unroll
    for (int n = 0; n < 4; ++n)
#pragma unroll
      for (int i = 0; i < 4; ++i)
        Plds[w][g * 4 + i][n * 16 + lr] = (bf16)p[n][i];
#pragma unroll
    for (int kk = 0; kk < 2; ++kk) {
      bf16x8 pa = *(const bf16x8*)(&Plds[w][lr][kk * 32 + g * 8]);
#pragma unroll
      for (int n = 0; n < 4; ++n) {
        bf16x8 bv = *(const bf16x8*)(Vb + (size_t)(n * 16 + lr) * 2048 + kv0 + kk * 32 + g * 8);
        oacc[n] = __builtin_amdgcn_mfma_f32_16x16x32_bf16(pa, bv, oacc[n], 0, 0, 0);
      }
    }
  }
#pragma unroll
  for (int i = 0; i < 4; ++i) l_i[i] = 1.f / l_i[i];
#pragma unroll
  for (int n = 0; n < 4; ++n)
#pragma unroll
    for (int i = 0; i < 4; ++i) {
      const int q = qt * 64 + w * 16 + g * 4 + i;
      Z[((size_t)(b * 2048 + q) * 16 + hh) * 64 + n * 16 + lr] = (bf16)(oacc[n][i] * l_i[i]);
    }
}

// ---------------- launcher ----------------
extern "C" void kernel_launch(void* const* d_in, const int* in_sizes, int n_in,
                              void* d_out, int out_size, void* d_ws, size_t ws_size,
                              hipStream_t stream) {
  const float* x  = (const float*)d_in[0];
  const float* WQ = (const float*)d_in[1];
  const float* WK = (const float*)d_in[2];
  const float* WV = (const float*)d_in[3];
  const float* WO = (const float*)d_in[4];
  const float* bQ = (const float*)d_in[5];
  const float* bK = (const float*)d_in[6];
  const float* bV = (const float*)d_in[7];
  const float* bO = (const float*)d_in[8];
  float* out = (float*)d_out;

  char* ws = (char*)d_ws;
  bf16* xb    = (bf16*)(ws);                        // 8 MB  [4096,1024]
  bf16* Wqkv  = (bf16*)(ws + (8u << 20));           // 6 MB  [3072,1024]
  bf16* Wo2   = (bf16*)(ws + (14u << 20));          // 2 MB  [1024,1024]
  bf16* Qb    = (bf16*)(ws + (16u << 20));          // 8 MB  [B,H,S,DH]
  bf16* Kb    = (bf16*)(ws + (24u << 20));          // 8 MB  [B,H,S,DH]
  bf16* Vtb   = (bf16*)(ws + (32u << 20));          // 8 MB  [B,H,DH,S]
  bf16* Zb    = (bf16*)(ws + (40u << 20));          // 8 MB  [4096,1024]
  float* biasq = (float*)(ws + (48u << 20));        // 12 KB [3072]

  castx_kernel<<<2048, 256, 0, stream>>>(x, xb);
  prep_kernel<<<2048, 256, 0, stream>>>(WQ, WK, WV, WO, bQ, bK, bV, Wqkv, Wo2, biasq);
  gemm_bt<0><<<dim3(32, 24), 256, 0, stream>>>(xb, Wqkv, biasq, Qb, Kb, Vtb, nullptr,
                                               4096, 3072, 1024);
  attn_kernel<<<dim3(32, 16, 2), 256, 0, stream>>>(Qb, Kb, Vtb, Zb);
  gemm_bt<1><<<dim3(32, 8), 256, 0, stream>>>(Zb, Wo2, bO, nullptr, nullptr, nullptr, out,
                                              4096, 1024, 1024);
}

// Round 3
// 231.977 us; speedup vs baseline: 2.0357x; 2.0357x over previous
//
#include <hip/hip_runtime.h>

// ---------------- types ----------------
typedef __bf16 bf16;
typedef __bf16 bf16x4 __attribute__((ext_vector_type(4)));
typedef __bf16 bf16x8 __attribute__((ext_vector_type(8)));
typedef float f32x4 __attribute__((ext_vector_type(4)));

#define AS1C(p) ((const __attribute__((address_space(1))) void*)(p))
#define AS3(p)  ((__attribute__((address_space(3))) void*)(p))

__device__ __forceinline__ void gld16(const bf16* gsrc, bf16* ldst) {
  // async global->LDS, 16 bytes/lane; LDS dest must be wave-uniform base (HW adds lane*16)
  __builtin_amdgcn_global_load_lds(AS1C(gsrc), AS3(ldst), 16, 0, 0);
}

// B=2, S=2048, D=1024, H=16, DH=64; M = B*S = 4096

// ---------------- cast x to bf16 ----------------
__global__ void castx_kernel(const float* __restrict__ x, bf16* __restrict__ xb) {
  const int n4 = (4096 * 1024) / 4;
  for (int i = blockIdx.x * blockDim.x + threadIdx.x; i < n4; i += gridDim.x * blockDim.x) {
    float4 v = ((const float4*)x)[i];
    bf16x4 o;
    o[0] = (bf16)v.x; o[1] = (bf16)v.y; o[2] = (bf16)v.z; o[3] = (bf16)v.w;
    ((bf16x4*)xb)[i] = o;
  }
}

// ---------------- prep weights: Wqkv (Q pre-scaled 1/8), Wo2 transpose, scaled biases ----------------
__global__ void prep_kernel(const float* __restrict__ WQ, const float* __restrict__ WK,
                            const float* __restrict__ WV, const float* __restrict__ WO,
                            const float* __restrict__ bQ, const float* __restrict__ bK,
                            const float* __restrict__ bV,
                            bf16* __restrict__ Wqkv, bf16* __restrict__ Wo2,
                            float* __restrict__ biasq) {
  const int WN = 1024 * 1024;
  const int total = 4 * WN + 3072;
  for (int i = blockIdx.x * blockDim.x + threadIdx.x; i < total; i += gridDim.x * blockDim.x) {
    if (i < WN) {
      Wqkv[i] = (bf16)(WQ[i] * 0.125f);          // fold 1/sqrt(DH) into Q
    } else if (i < 2 * WN) {
      Wqkv[i] = (bf16)WK[i - WN];
    } else if (i < 3 * WN) {
      Wqkv[i] = (bf16)WV[i - 2 * WN];
    } else if (i < 4 * WN) {
      int j = i - 3 * WN;                         // W_O flat [H][D][DH]
      int hh = j >> 16, r = j & 65535, d = r >> 6, dh = r & 63;
      Wo2[d * 1024 + hh * 64 + dh] = (bf16)WO[j]; // Wo2[d][h*64+dh]
    } else {
      int n = i - 4 * WN;
      biasq[n] = (n < 1024) ? bQ[n] * 0.125f : (n < 2048) ? bK[n - 1024] : bV[n - 2048];
    }
  }
}

// ---------------- GEMM C[M,N] = A[M,K] * Bw[N,K]^T  (bf16 in, f32 acc) ----------------
// MODE 0: QKV projection -> scatter Q[B,H,S,DH], K[B,H,S,DH], Vt[B,H,DH,S] (bf16, +bias)
// MODE 1: out projection -> Co[M,N] f32 (+bias)
template <int MODE>
__global__ __launch_bounds__(256)
void gemm_bt(const bf16* __restrict__ A, const bf16* __restrict__ Bw,
             const float* __restrict__ bias,
             bf16* __restrict__ Qo, bf16* __restrict__ Ko, bf16* __restrict__ Vt,
             float* __restrict__ Co, int M, int N, int K) {
  __shared__ bf16 As[128 * 64];
  __shared__ bf16 Bs[128 * 64];
  const int tid = threadIdx.x;
  const int lane = tid & 63, w = tid >> 6;
  const int wr = w >> 1, wc = w & 1;
  const int g = lane >> 4, lr = lane & 15;
  const int brow = blockIdx.x * 128, bcol = blockIdx.y * 128;

  f32x4 acc[4][4] = {};

  for (int k0 = 0; k0 < K; k0 += 64) {
#pragma unroll
    for (int it = 0; it < 4; ++it) {
      const int chunk = it * 4 + w;          // wave-uniform
      const int e = chunk * 64 + lane;       // 16B chunk id in tile
      const int row = e >> 3;
      const int c8 = (e & 7) << 3;
      gld16(A + (size_t)(brow + row) * K + k0 + c8, As + chunk * 512);
      gld16(Bw + (size_t)(bcol + row) * K + k0 + c8, Bs + chunk * 512);
    }
    __syncthreads();                          // drains vmcnt: tiles ready
#pragma unroll
    for (int kk = 0; kk < 2; ++kk) {
      bf16x8 af[4], bfm[4];
#pragma unroll
      for (int m = 0; m < 4; ++m)
        af[m] = *(const bf16x8*)(As + (wr * 64 + m * 16 + lr) * 64 + kk * 32 + g * 8);
#pragma unroll
      for (int n = 0; n < 4; ++n)
        bfm[n] = *(const bf16x8*)(Bs + (wc * 64 + n * 16 + lr) * 64 + kk * 32 + g * 8);
#pragma unroll
      for (int m = 0; m < 4; ++m)
#pragma unroll
        for (int n = 0; n < 4; ++n)
          acc[m][n] = __builtin_amdgcn_mfma_f32_16x16x32_bf16(af[m], bfm[n], acc[m][n], 0, 0, 0);
    }
    __syncthreads();                          // protect LDS before next stage
  }

  const int row0 = brow + wr * 64;
  const int col0 = bcol + wc * 64;
#pragma unroll
  for (int m = 0; m < 4; ++m) {
#pragma unroll
    for (int n = 0; n < 4; ++n) {
      const int nidx = col0 + n * 16 + lr;
      f32x4 v = acc[m][n];
      const float bs = bias[nidx];
      if (MODE == 0) {
        const int stream = nidx >> 10;        // 0=Q 1=K 2=V (uniform per 16-lane group)
        const int j = nidx & 1023;
        const int hh = j >> 6, dh = j & 63;
        const int r0 = row0 + m * 16 + g * 4; // token row base; i = 0..3 consecutive
        const int b = r0 >> 11;
        const int p0 = r0 & 2047;
        if (stream == 2) {
          bf16x4 vv;
#pragma unroll
          for (int i = 0; i < 4; ++i) vv[i] = (bf16)(v[i] + bs);
          *(bf16x4*)(Vt + ((size_t)(b * 16 + hh) * 64 + dh) * 2048 + p0) = vv;
        } else {
          bf16* dst = (stream == 0) ? Qo : Ko;
#pragma unroll
          for (int i = 0; i < 4; ++i)
            dst[((size_t)(b * 16 + hh) * 2048 + (p0 + i)) * 64 + dh] = (bf16)(v[i] + bs);
        }
      } else {
#pragma unroll
        for (int i = 0; i < 4; ++i) {
          const int r = row0 + m * 16 + g * 4 + i;
          Co[(size_t)r * 1024 + nidx] = v[i] + bs;
        }
      }
    }
  }
}

// ---------------- causal flash attention (v2: LDS-staged K/V, balanced q-tile pairs) ----
// grid: (16, H, B); block 256 = 4 waves. Block pi handles q-tiles {pi, 31-pi} -> 33 KV-tiles
// each. K/V staged via global_load_lds with XOR-swizzled source (linear LDS dest + swizzled
// read: involution s(c) = c ^ ((c>>3)&7) on 16B-chunk index). Double-buffered, 2-phase.
// Q,K: [B,H,S,DH] bf16 (Q pre-scaled); V: [B,H,DH,S] bf16. Z out: [B,S,H,DH] bf16.
__global__ __launch_bounds__(256, 2)
void attn_kernel(const bf16* __restrict__ Qm, const bf16* __restrict__ Km,
                 const bf16* __restrict__ Vm, bf16* __restrict__ Z) {
  const int pi = blockIdx.x, hh = blockIdx.y, b = blockIdx.z;
  const int bh = b * 16 + hh;
  const int lane = threadIdx.x & 63, w = threadIdx.x >> 6;
  const int g = lane >> 4, lr = lane & 15;
  __shared__ bf16 Ks[2][4096];               // [buf][64 kv rows][64 dh], swizzled chunks
  __shared__ bf16 Vs[2][4096];               // [buf][64 dh rows][64 kv], swizzled chunks
  __shared__ bf16 Plds[4][16][72];           // wave-private P tile, padded

  const bf16* Qb = Qm + (size_t)bh * 2048 * 64;
  const bf16* Kb = Km + (size_t)bh * 2048 * 64;
  const bf16* Vb = Vm + (size_t)bh * 64 * 2048;

  // stage one 64x64 K tile + 64x64 V tile into buffer bufi; tile starts at kv0.
  // LDS slot u (16B chunk) receives logical chunk lc = u ^ ((u>>3)&7)  (involution).
  auto stage = [&](int kv0, int bufi) {
#pragma unroll
    for (int it = 0; it < 2; ++it) {
      const int cb = w * 128 + it * 64;      // wave-uniform chunk base
      const int u = cb + lane;
      const int lc = u ^ ((u >> 3) & 7);
      const int row = lc >> 3, c8 = (lc & 7) * 8;
      gld16(Kb + (size_t)(kv0 + row) * 64 + c8, &Ks[bufi][cb * 8]);
      gld16(Vb + (size_t)row * 2048 + kv0 + c8, &Vs[bufi][cb * 8]);
    }
  };

  for (int half = 0; half < 2; ++half) {
    const int qt = half ? 31 - pi : pi;
    const int q0 = qt * 64 + w * 16;

    bf16x8 aq[2];
#pragma unroll
    for (int kk = 0; kk < 2; ++kk)
      aq[kk] = *(const bf16x8*)(Qb + (size_t)(q0 + lr) * 64 + kk * 32 + g * 8);

    float m_i[4], l_i[4];
    f32x4 oacc[4] = {};
#pragma unroll
    for (int i = 0; i < 4; ++i) { m_i[i] = -1e30f; l_i[i] = 0.f; }

    stage(0, 0);
    __syncthreads();                         // compiler drains vmcnt before barrier
    int buf = 0;

    for (int t = 0; t <= qt; ++t) {
      if (t < qt) stage((t + 1) * 64, buf ^ 1);   // prefetch next tile (overlaps compute)

      f32x4 s[4] = {};
#pragma unroll
      for (int kk = 0; kk < 2; ++kk) {
#pragma unroll
        for (int n = 0; n < 4; ++n) {
          const int r = n * 16 + lr;
          const int slot = (r * 8 + kk * 4 + g) ^ (r & 7);
          bf16x8 bk = *(const bf16x8*)(&Ks[buf][slot * 8]);
          s[n] = __builtin_amdgcn_mfma_f32_16x16x32_bf16(aq[kk], bk, s[n], 0, 0, 0);
        }
      }
      if (t == qt) {                         // diagonal tile: causal mask (tile-local idx)
#pragma unroll
        for (int n = 0; n < 4; ++n) {
          const int key = n * 16 + lr;
#pragma unroll
          for (int i = 0; i < 4; ++i) {
            const int rr = w * 16 + g * 4 + i;
            if (key > rr) s[n][i] = -1e9f;
          }
        }
      }
      float tm[4], ts[4], al[4];
#pragma unroll
      for (int i = 0; i < 4; ++i)
        tm[i] = fmaxf(fmaxf(s[0][i], s[1][i]), fmaxf(s[2][i], s[3][i]));
#pragma unroll
      for (int d = 1; d < 16; d <<= 1)
#pragma unroll
        for (int i = 0; i < 4; ++i) tm[i] = fmaxf(tm[i], __shfl_xor(tm[i], d));
#pragma unroll
      for (int i = 0; i < 4; ++i) {
        const float mn = fmaxf(m_i[i], tm[i]);
        al[i] = __expf(m_i[i] - mn);
        m_i[i] = mn;
      }
      f32x4 p[4];
#pragma unroll
      for (int n = 0; n < 4; ++n)
#pragma unroll
        for (int i = 0; i < 4; ++i) p[n][i] = __expf(s[n][i] - m_i[i]);
#pragma unroll
      for (int i = 0; i < 4; ++i) ts[i] = p[0][i] + p[1][i] + p[2][i] + p[3][i];
#pragma unroll
      for (int d = 1; d < 16; d <<= 1)
#pragma unroll
        for (int i = 0; i < 4; ++i) ts[i] += __shfl_xor(ts[i], d);
#pragma unroll
      for (int i = 0; i < 4; ++i) l_i[i] = l_i[i] * al[i] + ts[i];
#pragma unroll
      for (int n = 0; n < 4; ++n)
#pragma unroll
        for (int i = 0; i < 4; ++i) oacc[n][i] *= al[i];
      // P -> LDS (C-layout write), read back in A-frag layout
#pragma unroll
      for (int n = 0; n < 4; ++n)
#pragma unroll
        for (int i = 0; i < 4; ++i)
          Plds[w][g * 4 + i][n * 16 + lr] = (bf16)p[n][i];
#pragma unroll
      for (int kk = 0; kk < 2; ++kk) {
        bf16x8 pa = *(const bf16x8*)(&Plds[w][lr][kk * 32 + g * 8]);
#pragma unroll
        for (int n = 0; n < 4; ++n) {
          const int r = n * 16 + lr;
          const int slot = (r * 8 + kk * 4 + g) ^ (r & 7);
          bf16x8 bv = *(const bf16x8*)(&Vs[buf][slot * 8]);
          oacc[n] = __builtin_amdgcn_mfma_f32_16x16x32_bf16(pa, bv, oacc[n], 0, 0, 0);
        }
      }
      __syncthreads();                       // drains prefetch vmcnt + aligns buffer swap
      buf ^= 1;
    }

#pragma unroll
    for (int i = 0; i < 4; ++i) l_i[i] = 1.f / l_i[i];
#pragma unroll
    for (int n = 0; n < 4; ++n)
#pragma unroll
      for (int i = 0; i < 4; ++i) {
        const int q = qt * 64 + w * 16 + g * 4 + i;
        Z[((size_t)(b * 2048 + q) * 16 + hh) * 64 + n * 16 + lr] = (bf16)(oacc[n][i] * l_i[i]);
      }
  }
}

// ---------------- launcher ----------------
extern "C" void kernel_launch(void* const* d_in, const int* in_sizes, int n_in,
                              void* d_out, int out_size, void* d_ws, size_t ws_size,
                              hipStream_t stream) {
  const float* x  = (const float*)d_in[0];
  const float* WQ = (const float*)d_in[1];
  const float* WK = (const float*)d_in[2];
  const float* WV = (const float*)d_in[3];
  const float* WO = (const float*)d_in[4];
  const float* bQ = (const float*)d_in[5];
  const float* bK = (const float*)d_in[6];
  const float* bV = (const float*)d_in[7];
  const float* bO = (const float*)d_in[8];
  float* out = (float*)d_out;

  char* ws = (char*)d_ws;
  bf16* xb    = (bf16*)(ws);                        // 8 MB  [4096,1024]
  bf16* Wqkv  = (bf16*)(ws + (8u << 20));           // 6 MB  [3072,1024]
  bf16* Wo2   = (bf16*)(ws + (14u << 20));          // 2 MB  [1024,1024]
  bf16* Qb    = (bf16*)(ws + (16u << 20));          // 8 MB  [B,H,S,DH]
  bf16* Kb    = (bf16*)(ws + (24u << 20));          // 8 MB  [B,H,S,DH]
  bf16* Vtb   = (bf16*)(ws + (32u << 20));          // 8 MB  [B,H,DH,S]
  bf16* Zb    = (bf16*)(ws + (40u << 20));          // 8 MB  [4096,1024]
  float* biasq = (float*)(ws + (48u << 20));        // 12 KB [3072]

  castx_kernel<<<2048, 256, 0, stream>>>(x, xb);
  prep_kernel<<<2048, 256, 0, stream>>>(WQ, WK, WV, WO, bQ, bK, bV, Wqkv, Wo2, biasq);
  gemm_bt<0><<<dim3(32, 24), 256, 0, stream>>>(xb, Wqkv, biasq, Qb, Kb, Vtb, nullptr,
                                               4096, 3072, 1024);
  attn_kernel<<<dim3(16, 16, 2), 256, 0, stream>>>(Qb, Kb, Vtb, Zb);
  gemm_bt<1><<<dim3(32, 8), 256, 0, stream>>>(Zb, Wo2, bO, nullptr, nullptr, nullptr, out,
                                              4096, 1024, 1024);
}